// Round 1
// baseline (1023.920 us; speedup 1.0000x reference)
//
#include <hip/hip_runtime.h>
#include <hip/hip_bf16.h>

// NettackSurrogate: out = Ahat^2 @ (x @ W), Ahat = D^-1/2 (A_noself + I) D^-1/2
// N=100000 nodes, E=3200000 edges, IN=512, OUT=64, fp32.
//
// Pipeline (all on `stream`, graph-capture safe):
//  1) memset cnt=0
//  2) deg_kernel: histogram of row (non-self edges) via int atomics
//  3) scan_part/scan_mid/scan_fix: exclusive scan -> rowptr, dinv, cursor
//  4) scatter_kernel: build CSR (csr_col, csr_norm = dinv[r]*dinv[c])
//  5) gemm_kernel: h0 = x @ W  (fp32, LDS-tiled, 4x4 register blocking)
//  6) prop_kernel: h1 = Ahat @ h0   (1 wave per node, lane = channel)
//  7) prop_kernel: out = Ahat @ h1

#define OUTC 64
#define INC 512

__global__ __launch_bounds__(256) void deg_kernel(const int* __restrict__ erow,
                                                  const int* __restrict__ ecol,
                                                  int* __restrict__ cnt, int nE) {
    int e = blockIdx.x * 256 + threadIdx.x;
    if (e >= nE) return;
    int r = erow[e];
    int c = ecol[e];
    if (r != c) atomicAdd(&cnt[r], 1);
}

// Each block scans 1024 elements (4 per thread) of cnt (padded with 0 past n).
// Writes local-exclusive prefix into rowptr, block total into chunkSum.
__global__ __launch_bounds__(256) void scan_part(const int* __restrict__ cnt,
                                                 int* __restrict__ rowptr,
                                                 int* __restrict__ chunkSum,
                                                 int n, int ntot) {
    __shared__ int sdata[256];
    const int t = threadIdx.x;
    const int base = blockIdx.x * 1024;
    int v[4];
    int s = 0;
#pragma unroll
    for (int i = 0; i < 4; ++i) {
        int idx = base + t * 4 + i;
        v[i] = (idx < n) ? cnt[idx] : 0;
        s += v[i];
    }
    sdata[t] = s;
    __syncthreads();
    // Hillis-Steele inclusive scan over 256 thread sums
    for (int off = 1; off < 256; off <<= 1) {
        int xval = 0;
        if (t >= off) xval = sdata[t - off];
        __syncthreads();
        sdata[t] += xval;
        __syncthreads();
    }
    if (t == 255) chunkSum[blockIdx.x] = sdata[255];
    int run = sdata[t] - s;  // exclusive prefix of this thread's 4 elements
#pragma unroll
    for (int i = 0; i < 4; ++i) {
        int idx = base + t * 4 + i;
        if (idx < ntot) rowptr[idx] = run;
        run += v[i];
    }
}

// Single block: exclusive scan of chunkSum[0..nchunks) -> chunkOff. nchunks <= 128.
__global__ __launch_bounds__(128) void scan_mid(const int* __restrict__ chunkSum,
                                                int* __restrict__ chunkOff, int nchunks) {
    __shared__ int sdata[128];
    const int t = threadIdx.x;
    int own = (t < nchunks) ? chunkSum[t] : 0;
    sdata[t] = own;
    __syncthreads();
    for (int off = 1; off < 128; off <<= 1) {
        int xval = 0;
        if (t >= off) xval = sdata[t - off];
        __syncthreads();
        sdata[t] += xval;
        __syncthreads();
    }
    if (t < nchunks) chunkOff[t] = sdata[t] - own;
}

__global__ __launch_bounds__(256) void scan_fix(int* __restrict__ rowptr,
                                                const int* __restrict__ chunkOff,
                                                const int* __restrict__ cnt,
                                                float* __restrict__ dinv,
                                                int* __restrict__ cursor, int n) {
    int idx = blockIdx.x * 256 + threadIdx.x;
    if (idx > n) return;
    int rp = rowptr[idx] + chunkOff[idx >> 10];
    rowptr[idx] = rp;
    if (idx < n) {
        dinv[idx] = rsqrtf((float)cnt[idx] + 1.0f);
        cursor[idx] = rp;
    }
}

__global__ __launch_bounds__(256) void scatter_kernel(const int* __restrict__ erow,
                                                      const int* __restrict__ ecol,
                                                      int* __restrict__ cursor,
                                                      const float* __restrict__ dinv,
                                                      int* __restrict__ csr_col,
                                                      float* __restrict__ csr_norm, int nE) {
    int e = blockIdx.x * 256 + threadIdx.x;
    if (e >= nE) return;
    int r = erow[e];
    int c = ecol[e];
    if (r != c) {
        int p = atomicAdd(&cursor[r], 1);
        csr_col[p] = c;
        csr_norm[p] = dinv[r] * dinv[c];
    }
}

// h0[n][64] = x[n][512] @ W[512][64], fp32.
// Block tile: 64 nodes x 64 ch; thread (ng,cg) in 16x16 grid owns 4 nodes x 4 ch.
__global__ __launch_bounds__(256) void gemm_kernel(const float* __restrict__ x,
                                                   const float* __restrict__ W,
                                                   float* __restrict__ h, int n) {
    __shared__ float sW[32][OUTC];            // 8 KB
    __shared__ __align__(16) float sX[32][68]; // transposed x tile, +4 pad (16B-aligned rows)
    const int t = threadIdx.x;
    const int ng = t & 15;
    const int cg = t >> 4;
    const int m0 = blockIdx.x * 64;
    float acc[4][4];
#pragma unroll
    for (int i = 0; i < 4; ++i)
#pragma unroll
        for (int j = 0; j < 4; ++j) acc[i][j] = 0.0f;

    for (int k0 = 0; k0 < INC; k0 += 32) {
#pragma unroll
        for (int i = 0; i < 8; ++i) {  // stage W: 32x64
            int idx = i * 256 + t;
            int kk = idx >> 6, cc = idx & 63;
            sW[kk][cc] = W[(k0 + kk) * OUTC + cc];
        }
#pragma unroll
        for (int i = 0; i < 8; ++i) {  // stage x transposed: 64 nodes x 32 k
            int idx = i * 256 + t;
            int node = idx >> 5, kk = idx & 31;
            int gn = m0 + node;
            sX[kk][node] = (gn < n) ? x[gn * INC + k0 + kk] : 0.0f;
        }
        __syncthreads();
#pragma unroll 8
        for (int kk = 0; kk < 32; ++kk) {
            float4 xv = *(const float4*)&sX[kk][ng * 4];
            float4 wv = *(const float4*)&sW[kk][cg * 4];
            acc[0][0] += xv.x * wv.x; acc[0][1] += xv.x * wv.y; acc[0][2] += xv.x * wv.z; acc[0][3] += xv.x * wv.w;
            acc[1][0] += xv.y * wv.x; acc[1][1] += xv.y * wv.y; acc[1][2] += xv.y * wv.z; acc[1][3] += xv.y * wv.w;
            acc[2][0] += xv.z * wv.x; acc[2][1] += xv.z * wv.y; acc[2][2] += xv.z * wv.z; acc[2][3] += xv.z * wv.w;
            acc[3][0] += xv.w * wv.x; acc[3][1] += xv.w * wv.y; acc[3][2] += xv.w * wv.z; acc[3][3] += xv.w * wv.w;
        }
        __syncthreads();
    }
#pragma unroll
    for (int i = 0; i < 4; ++i) {
        int gn = m0 + ng * 4 + i;
        if (gn < n) {
            float4 o = make_float4(acc[i][0], acc[i][1], acc[i][2], acc[i][3]);
            *(float4*)&h[gn * OUTC + cg * 4] = o;
        }
    }
}

// One wave per destination node; lane = output channel.
// acc = self_norm*hin[node] + sum_e norm_e * hin[col_e]
__global__ __launch_bounds__(256) void prop_kernel(const float* __restrict__ hin,
                                                   float* __restrict__ hout,
                                                   const int* __restrict__ rowptr,
                                                   const int* __restrict__ csr_col,
                                                   const float* __restrict__ csr_norm,
                                                   const float* __restrict__ dinv, int n) {
    const int lane = threadIdx.x & 63;
    const int node = blockIdx.x * 4 + (threadIdx.x >> 6);
    if (node >= n) return;
    float di = dinv[node];
    float acc = di * di * hin[node * OUTC + lane];
    const int jb = rowptr[node];
    const int je = rowptr[node + 1];
    for (int j = jb; j < je; j += 64) {
        int m = je - j;
        if (m > 64) m = 64;
        int colv = 0;
        float wv = 0.0f;
        if (lane < m) {
            colv = csr_col[j + lane];
            wv = csr_norm[j + lane];
        }
        int tt = 0;
        for (; tt + 4 <= m; tt += 4) {
            int c0 = __shfl(colv, tt);     float w0 = __shfl(wv, tt);
            int c1 = __shfl(colv, tt + 1); float w1 = __shfl(wv, tt + 1);
            int c2 = __shfl(colv, tt + 2); float w2 = __shfl(wv, tt + 2);
            int c3 = __shfl(colv, tt + 3); float w3 = __shfl(wv, tt + 3);
            float g0 = hin[c0 * OUTC + lane];
            float g1 = hin[c1 * OUTC + lane];
            float g2 = hin[c2 * OUTC + lane];
            float g3 = hin[c3 * OUTC + lane];
            acc += w0 * g0;
            acc += w1 * g1;
            acc += w2 * g2;
            acc += w3 * g3;
        }
        for (; tt < m; ++tt) {
            int c = __shfl(colv, tt);
            float w = __shfl(wv, tt);
            acc += w * hin[c * OUTC + lane];
        }
    }
    hout[node * OUTC + lane] = acc;
}

extern "C" void kernel_launch(void* const* d_in, const int* in_sizes, int n_in,
                              void* d_out, int out_size, void* d_ws, size_t ws_size,
                              hipStream_t stream) {
    const int n = out_size / OUTC;       // 100000
    const int nE = in_sizes[0] / 2;      // 3200000
    const int* erow = (const int*)d_in[0];
    const int* ecol = erow + nE;
    const float* x = (const float*)d_in[1];
    const float* W = (const float*)d_in[2];
    float* out = (float*)d_out;

    // workspace carve (256B aligned)
    char* base = (char*)d_ws;
    size_t off = 0;
    auto take = [&](size_t nbytes) -> void* {
        void* p = base + off;
        off += (nbytes + 255) & ~(size_t)255;
        return p;
    };
    int* cnt = (int*)take((size_t)n * 4);
    int* rowptr = (int*)take((size_t)(n + 1) * 4);
    int* cursor = (int*)take((size_t)n * 4);
    float* dinv = (float*)take((size_t)n * 4);
    int* chunkSum = (int*)take(128 * 4);
    int* chunkOff = (int*)take(128 * 4);
    int* csr_col = (int*)take((size_t)nE * 4);
    float* csr_norm = (float*)take((size_t)nE * 4);
    float* h0 = (float*)take((size_t)n * OUTC * 4);
    float* h1 = (float*)take((size_t)n * OUTC * 4);

    hipMemsetAsync(cnt, 0, (size_t)n * 4, stream);

    deg_kernel<<<(nE + 255) / 256, 256, 0, stream>>>(erow, ecol, cnt, nE);

    const int ntot = n + 1;
    const int nchunks = (ntot + 1023) / 1024;  // 98 for n=100000
    scan_part<<<nchunks, 256, 0, stream>>>(cnt, rowptr, chunkSum, n, ntot);
    scan_mid<<<1, 128, 0, stream>>>(chunkSum, chunkOff, nchunks);
    scan_fix<<<(ntot + 255) / 256, 256, 0, stream>>>(rowptr, chunkOff, cnt, dinv, cursor, n);

    scatter_kernel<<<(nE + 255) / 256, 256, 0, stream>>>(erow, ecol, cursor, dinv, csr_col,
                                                         csr_norm, nE);

    gemm_kernel<<<(n + 63) / 64, 256, 0, stream>>>(x, W, h0, n);

    prop_kernel<<<(n + 3) / 4, 256, 0, stream>>>(h0, h1, rowptr, csr_col, csr_norm, dinv, n);
    prop_kernel<<<(n + 3) / 4, 256, 0, stream>>>(h1, out, rowptr, csr_col, csr_norm, dinv, n);
}

// Round 2
// 909.748 us; speedup vs baseline: 1.1255x; 1.1255x over previous
//
#include <hip/hip_runtime.h>
#include <hip/hip_bf16.h>

// NettackSurrogate: out = Ahat^2 @ (x @ W), Ahat = D^-1/2 (A_noself + I) D^-1/2
// N=100000 nodes, E=3200000 edges, IN=512, OUT=64, fp32.
//
// dinv factorization: norm_rc = dinv_r*dinv_c, so with hs = dinv (.) h:
//   hop: h'_r = dinv_r * (hs_r + sum_{c in N(r)} hs_c)
//   hs1 = dinv (.) h' = dinv_r^2 * (hs_r + sum hs_c)   <- intermediate hop output
//   out_r = dinv_r * (hs1_r + sum hs1_c)               <- final hop output
// => no per-edge norm array needed; CSR stores col only.
//
// Scatter/deg write-amplification fix: random 4B stores from all 8 XCDs give
// ~8 partial-line writebacks per 64B line (R1: WRITE_SIZE=295MB for 25.6MB
// payload). Partition rows into 8 groups, group = blockIdx&7 (round-robin
// blockIdx->XCD heuristic): all writers of a line sit on one XCD, line fills
// in one L2, writes back once. Costs 8x sequential edge reads (205MB ~ 33us).

#define OUTC 64
#define INC 512
#define NGROUP 8
#define BLK_PER_GROUP 128

__global__ __launch_bounds__(256) void deg_part(const int* __restrict__ erow,
                                                int* __restrict__ cnt, int nE, int n) {
    const int g = blockIdx.x & (NGROUP - 1);
    const int bi = blockIdx.x >> 3;
    const int stride = BLK_PER_GROUP * 256;
    const int lo = (int)((long long)n * g / NGROUP);
    const int hi = (int)((long long)n * (g + 1) / NGROUP);
    for (int e = bi * 256 + threadIdx.x; e < nE; e += stride) {
        int r = erow[e];
        if (r < lo || r >= hi) continue;
        int c = erow[nE + e];  // ecol
        if (r == c) continue;
        atomicAdd(&cnt[r], 1);
    }
}

// Each block scans 1024 elements (4 per thread) of cnt (padded with 0 past n).
__global__ __launch_bounds__(256) void scan_part(const int* __restrict__ cnt,
                                                 int* __restrict__ rowptr,
                                                 int* __restrict__ chunkSum,
                                                 int n, int ntot) {
    __shared__ int sdata[256];
    const int t = threadIdx.x;
    const int base = blockIdx.x * 1024;
    int v[4];
    int s = 0;
#pragma unroll
    for (int i = 0; i < 4; ++i) {
        int idx = base + t * 4 + i;
        v[i] = (idx < n) ? cnt[idx] : 0;
        s += v[i];
    }
    sdata[t] = s;
    __syncthreads();
    for (int off = 1; off < 256; off <<= 1) {
        int xval = 0;
        if (t >= off) xval = sdata[t - off];
        __syncthreads();
        sdata[t] += xval;
        __syncthreads();
    }
    if (t == 255) chunkSum[blockIdx.x] = sdata[255];
    int run = sdata[t] - s;
#pragma unroll
    for (int i = 0; i < 4; ++i) {
        int idx = base + t * 4 + i;
        if (idx < ntot) rowptr[idx] = run;
        run += v[i];
    }
}

__global__ __launch_bounds__(128) void scan_mid(const int* __restrict__ chunkSum,
                                                int* __restrict__ chunkOff, int nchunks) {
    __shared__ int sdata[128];
    const int t = threadIdx.x;
    int own = (t < nchunks) ? chunkSum[t] : 0;
    sdata[t] = own;
    __syncthreads();
    for (int off = 1; off < 128; off <<= 1) {
        int xval = 0;
        if (t >= off) xval = sdata[t - off];
        __syncthreads();
        sdata[t] += xval;
        __syncthreads();
    }
    if (t < nchunks) chunkOff[t] = sdata[t] - own;
}

__global__ __launch_bounds__(256) void scan_fix(int* __restrict__ rowptr,
                                                const int* __restrict__ chunkOff,
                                                const int* __restrict__ cnt,
                                                float* __restrict__ dinv,
                                                int* __restrict__ cursor, int n) {
    int idx = blockIdx.x * 256 + threadIdx.x;
    if (idx > n) return;
    int rp = rowptr[idx] + chunkOff[idx >> 10];
    rowptr[idx] = rp;
    if (idx < n) {
        dinv[idx] = rsqrtf((float)cnt[idx] + 1.0f);
        cursor[idx] = rp;
    }
}

__global__ __launch_bounds__(256) void scatter_part(const int* __restrict__ erow,
                                                    int* __restrict__ cursor,
                                                    int* __restrict__ csr_col,
                                                    int nE, int n) {
    const int g = blockIdx.x & (NGROUP - 1);
    const int bi = blockIdx.x >> 3;
    const int stride = BLK_PER_GROUP * 256;
    const int lo = (int)((long long)n * g / NGROUP);
    const int hi = (int)((long long)n * (g + 1) / NGROUP);
    for (int e = bi * 256 + threadIdx.x; e < nE; e += stride) {
        int r = erow[e];
        if (r < lo || r >= hi) continue;
        int c = erow[nE + e];  // ecol
        if (r == c) continue;
        int p = atomicAdd(&cursor[r], 1);
        csr_col[p] = c;
    }
}

// hs0[n][64] = dinv[n] * (x[n][512] @ W[512][64]), fp32.
__global__ __launch_bounds__(256) void gemm_kernel(const float* __restrict__ x,
                                                   const float* __restrict__ W,
                                                   const float* __restrict__ dinv,
                                                   float* __restrict__ h, int n) {
    __shared__ float sW[32][OUTC];             // 8 KB
    __shared__ __align__(16) float sX[32][68]; // transposed x tile, +4 pad
    const int t = threadIdx.x;
    const int ng = t & 15;
    const int cg = t >> 4;
    const int m0 = blockIdx.x * 64;
    float acc[4][4];
#pragma unroll
    for (int i = 0; i < 4; ++i)
#pragma unroll
        for (int j = 0; j < 4; ++j) acc[i][j] = 0.0f;

    for (int k0 = 0; k0 < INC; k0 += 32) {
#pragma unroll
        for (int i = 0; i < 8; ++i) {  // stage W: 32x64
            int idx = i * 256 + t;
            int kk = idx >> 6, cc = idx & 63;
            sW[kk][cc] = W[(k0 + kk) * OUTC + cc];
        }
#pragma unroll
        for (int i = 0; i < 8; ++i) {  // stage x transposed: 64 nodes x 32 k
            int idx = i * 256 + t;
            int node = idx >> 5, kk = idx & 31;
            int gn = m0 + node;
            sX[kk][node] = (gn < n) ? x[gn * INC + k0 + kk] : 0.0f;
        }
        __syncthreads();
#pragma unroll 8
        for (int kk = 0; kk < 32; ++kk) {
            float4 xv = *(const float4*)&sX[kk][ng * 4];
            float4 wv = *(const float4*)&sW[kk][cg * 4];
            acc[0][0] += xv.x * wv.x; acc[0][1] += xv.x * wv.y; acc[0][2] += xv.x * wv.z; acc[0][3] += xv.x * wv.w;
            acc[1][0] += xv.y * wv.x; acc[1][1] += xv.y * wv.y; acc[1][2] += xv.y * wv.z; acc[1][3] += xv.y * wv.w;
            acc[2][0] += xv.z * wv.x; acc[2][1] += xv.z * wv.y; acc[2][2] += xv.z * wv.z; acc[2][3] += xv.z * wv.w;
            acc[3][0] += xv.w * wv.x; acc[3][1] += xv.w * wv.y; acc[3][2] += xv.w * wv.z; acc[3][3] += xv.w * wv.w;
        }
        __syncthreads();
    }
#pragma unroll
    for (int i = 0; i < 4; ++i) {
        int gn = m0 + ng * 4 + i;
        if (gn < n) {
            float s = dinv[gn];
            float4 o = make_float4(acc[i][0] * s, acc[i][1] * s, acc[i][2] * s, acc[i][3] * s);
            *(float4*)&h[gn * OUTC + cg * 4] = o;
        }
    }
}

// One wave per destination node; lane = output channel.
// acc = hs[node] + sum_e hs[col_e];  hout = scale * acc
// finalhop=0: scale=dinv^2 (output is hs for next hop); finalhop=1: scale=dinv.
__global__ __launch_bounds__(256) void prop_kernel(const float* __restrict__ hs,
                                                   float* __restrict__ hout,
                                                   const int* __restrict__ rowptr,
                                                   const int* __restrict__ csr_col,
                                                   const float* __restrict__ dinv,
                                                   int n, int finalhop) {
    const int lane = threadIdx.x & 63;
    const int node = blockIdx.x * 4 + (threadIdx.x >> 6);
    if (node >= n) return;
    float acc = hs[node * OUTC + lane];
    const int jb = rowptr[node];
    const int je = rowptr[node + 1];
    for (int j = jb; j < je; j += 64) {
        int m = je - j;
        if (m > 64) m = 64;
        int colv = 0;
        if (lane < m) colv = csr_col[j + lane];
        int tt = 0;
        for (; tt + 4 <= m; tt += 4) {
            int c0 = __shfl(colv, tt);
            int c1 = __shfl(colv, tt + 1);
            int c2 = __shfl(colv, tt + 2);
            int c3 = __shfl(colv, tt + 3);
            float g0 = hs[c0 * OUTC + lane];
            float g1 = hs[c1 * OUTC + lane];
            float g2 = hs[c2 * OUTC + lane];
            float g3 = hs[c3 * OUTC + lane];
            acc += g0;
            acc += g1;
            acc += g2;
            acc += g3;
        }
        for (; tt < m; ++tt) {
            int c = __shfl(colv, tt);
            acc += hs[c * OUTC + lane];
        }
    }
    float di = dinv[node];
    float scale = finalhop ? di : di * di;
    hout[node * OUTC + lane] = scale * acc;
}

extern "C" void kernel_launch(void* const* d_in, const int* in_sizes, int n_in,
                              void* d_out, int out_size, void* d_ws, size_t ws_size,
                              hipStream_t stream) {
    const int n = out_size / OUTC;       // 100000
    const int nE = in_sizes[0] / 2;      // 3200000
    const int* erow = (const int*)d_in[0];  // [0..nE) = row, [nE..2nE) = col
    const float* x = (const float*)d_in[1];
    const float* W = (const float*)d_in[2];
    float* out = (float*)d_out;

    char* base = (char*)d_ws;
    size_t off = 0;
    auto take = [&](size_t nbytes) -> void* {
        void* p = base + off;
        off += (nbytes + 255) & ~(size_t)255;
        return p;
    };
    int* cnt = (int*)take((size_t)n * 4);
    int* rowptr = (int*)take((size_t)(n + 1) * 4);
    int* cursor = (int*)take((size_t)n * 4);
    float* dinv = (float*)take((size_t)n * 4);
    int* chunkSum = (int*)take(128 * 4);
    int* chunkOff = (int*)take(128 * 4);
    int* csr_col = (int*)take((size_t)nE * 4);
    float* h0 = (float*)take((size_t)n * OUTC * 4);
    float* h1 = (float*)take((size_t)n * OUTC * 4);

    hipMemsetAsync(cnt, 0, (size_t)n * 4, stream);

    deg_part<<<NGROUP * BLK_PER_GROUP, 256, 0, stream>>>(erow, cnt, nE, n);

    const int ntot = n + 1;
    const int nchunks = (ntot + 1023) / 1024;
    scan_part<<<nchunks, 256, 0, stream>>>(cnt, rowptr, chunkSum, n, ntot);
    scan_mid<<<1, 128, 0, stream>>>(chunkSum, chunkOff, nchunks);
    scan_fix<<<(ntot + 255) / 256, 256, 0, stream>>>(rowptr, chunkOff, cnt, dinv, cursor, n);

    scatter_part<<<NGROUP * BLK_PER_GROUP, 256, 0, stream>>>(erow, cursor, csr_col, nE, n);

    gemm_kernel<<<(n + 63) / 64, 256, 0, stream>>>(x, W, dinv, h0, n);

    prop_kernel<<<(n + 3) / 4, 256, 0, stream>>>(h0, h1, rowptr, csr_col, dinv, n, 0);
    prop_kernel<<<(n + 3) / 4, 256, 0, stream>>>(h1, out, rowptr, csr_col, dinv, n, 1);
}